// Round 1
// baseline (292.483 us; speedup 1.0000x reference)
//
#include <hip/hip_runtime.h>
#include <hip/hip_bf16.h>

#define N 128
#define NN (N * N)          // 16384
#define M 2048

// ---------------------------------------------------------------------------
// Prep kernel: build matH (Hr at ws[0..NN), Hi at ws[NN..2*NN)) from theta/evl
// ---------------------------------------------------------------------------
__device__ __forceinline__ float block_reduce128(float v, float* red, int i) {
    __syncthreads();                 // protect previous use of red[]
    red[i] = v;
    __syncthreads();
    for (int off = 64; off > 0; off >>= 1) {
        if (i < off) red[i] += red[i + off];
        __syncthreads();
    }
    return red[0];
}

__global__ void prep_kernel(const float* __restrict__ theta,
                            const float* __restrict__ evl,
                            float* __restrict__ H) {
    __shared__ float e0r[N], e0i[N], e1r[N], e1i[N];
    __shared__ float red[N];
    __shared__ float s_lam0, s_lam1;
    const int i = threadIdx.x;       // 128 threads

    // evc0 = c0 / |c0|
    float c0r = theta[i], c0i = theta[N + i];
    float s0 = block_reduce128(c0r * c0r + c0i * c0i, red, i);
    float inv0 = rsqrtf(s0);
    float a0r = c0r * inv0, a0i = c0i * inv0;
    e0r[i] = a0r; e0i[i] = a0i;

    // c1 -= vdot(evc0, c1) * evc0   (vdot conjugates first arg)
    float c1r = theta[2 * N + i], c1i = theta[3 * N + i];
    float dr = block_reduce128(a0r * c1r + a0i * c1i, red, i);
    float di = block_reduce128(a0r * c1i - a0i * c1r, red, i);
    c1r -= dr * a0r - di * a0i;
    c1i -= dr * a0i + di * a0r;

    // evc1 = c1 / |c1|
    float s1 = block_reduce128(c1r * c1r + c1i * c1i, red, i);
    float inv1 = rsqrtf(s1);
    float a1r = c1r * inv1, a1i = c1i * inv1;
    e1r[i] = a1r; e1i[i] = a1i;

    if (i == 0) {
        float l0 = log1pf(expf(evl[0]));   // softplus
        float l1 = log1pf(expf(evl[1]));
        float inl = rsqrtf(l0 * l0 + l1 * l1);
        s_lam0 = l0 * inl;
        s_lam1 = l1 * inl;
    }
    __syncthreads();                 // also publishes e1r/e1i to all threads
    const float lam0 = s_lam0, lam1 = s_lam1;

    // matH[i][j] = lam0*evc0[i]*conj(evc0[j]) - lam1*evc1[i]*conj(evc1[j])
    // (a+bi)(c-di) = (ac+bd) + i(bc-ad)
    for (int j = 0; j < N; ++j) {
        float c0rj = e0r[j], c0ij = e0i[j];
        float c1rj = e1r[j], c1ij = e1i[j];
        float hr = lam0 * (a0r * c0rj + a0i * c0ij)
                 - lam1 * (a1r * c1rj + a1i * c1ij);
        float hi = lam0 * (a0i * c0rj - a0r * c0ij)
                 - lam1 * (a1i * c1rj - a1r * c1ij);
        H[i * N + j]      = hr;
        H[NN + i * N + j] = hi;
    }
}

// ---------------------------------------------------------------------------
// Main kernel: one block per basis operator.
// v_k = sum_t (br - i*bi) * (Hr + i*Hi); out += |v_k|^2
// ---------------------------------------------------------------------------
__global__ __launch_bounds__(256) void main_kernel(
        const float4* __restrict__ br, const float4* __restrict__ bi,
        const float4* __restrict__ H, float* __restrict__ out) {
    const int k = blockIdx.x;
    const int t = threadIdx.x;
    const float4* brk = br + (size_t)k * (NN / 4);
    const float4* bik = bi + (size_t)k * (NN / 4);
    const float4* Hr = H;
    const float4* Hi = H + (NN / 4);

    float vr = 0.f, vi = 0.f;
    #pragma unroll 4
    for (int it = t; it < NN / 4; it += 256) {
        float4 a  = brk[it];
        float4 b  = bik[it];
        float4 hr = Hr[it];
        float4 hi = Hi[it];
        vr += a.x * hr.x + b.x * hi.x;  vi += a.x * hi.x - b.x * hr.x;
        vr += a.y * hr.y + b.y * hi.y;  vi += a.y * hi.y - b.y * hr.y;
        vr += a.z * hr.z + b.z * hi.z;  vi += a.z * hi.z - b.z * hr.z;
        vr += a.w * hr.w + b.w * hi.w;  vi += a.w * hi.w - b.w * hr.w;
    }

    // wave-64 reduce
    for (int off = 32; off > 0; off >>= 1) {
        vr += __shfl_down(vr, off);
        vi += __shfl_down(vi, off);
    }
    __shared__ float swr[4], swi[4];
    const int wave = t >> 6, lane = t & 63;
    if (lane == 0) { swr[wave] = vr; swi[wave] = vi; }
    __syncthreads();
    if (t == 0) {
        float R = swr[0] + swr[1] + swr[2] + swr[3];
        float I = swi[0] + swi[1] + swi[2] + swi[3];
        atomicAdd(out, R * R + I * I);
    }
}

extern "C" void kernel_launch(void* const* d_in, const int* in_sizes, int n_in,
                              void* d_out, int out_size, void* d_ws, size_t ws_size,
                              hipStream_t stream) {
    const float* basis_re = (const float*)d_in[0];
    const float* basis_im = (const float*)d_in[1];
    const float* theta    = (const float*)d_in[2];
    const float* evl      = (const float*)d_in[3];
    float* out = (float*)d_out;
    float* H   = (float*)d_ws;   // 2*NN floats = 128 KiB

    hipMemsetAsync(d_out, 0, sizeof(float), stream);
    prep_kernel<<<1, 128, 0, stream>>>(theta, evl, H);
    main_kernel<<<M, 256, 0, stream>>>((const float4*)basis_re,
                                       (const float4*)basis_im,
                                       (const float4*)H, out);
}

// Round 2
// 285.957 us; speedup vs baseline: 1.0228x; 1.0228x over previous
//
#include <hip/hip_runtime.h>

#define N 128
#define NN (N * N)          // 16384
#define M 2048

// ---------------------------------------------------------------------------
// Prep: compute evc0, evc1 (Gram-Schmidt) and normalized softplus eigenvalues.
// ws layout: [0..128) e0r | [128..256) e0i | [256..384) e1r | [384..512) e1i
//            [512] lam0 | [513] lam1
// ---------------------------------------------------------------------------
__device__ __forceinline__ float block_reduce128(float v, float* red, int i) {
    __syncthreads();
    red[i] = v;
    __syncthreads();
    for (int off = 64; off > 0; off >>= 1) {
        if (i < off) red[i] += red[i + off];
        __syncthreads();
    }
    return red[0];
}

__global__ void prep_kernel(const float* __restrict__ theta,
                            const float* __restrict__ evl,
                            float* __restrict__ ws) {
    __shared__ float red[N];
    const int i = threadIdx.x;   // 128 threads

    float c0r = theta[i], c0i = theta[N + i];
    float s0 = block_reduce128(c0r * c0r + c0i * c0i, red, i);
    float inv0 = rsqrtf(s0);
    float a0r = c0r * inv0, a0i = c0i * inv0;

    // c1 -= vdot(evc0, c1) * evc0   (vdot conjugates first arg)
    float c1r = theta[2 * N + i], c1i = theta[3 * N + i];
    float dr = block_reduce128(a0r * c1r + a0i * c1i, red, i);
    float di = block_reduce128(a0r * c1i - a0i * c1r, red, i);
    c1r -= dr * a0r - di * a0i;
    c1i -= dr * a0i + di * a0r;

    float s1 = block_reduce128(c1r * c1r + c1i * c1i, red, i);
    float inv1 = rsqrtf(s1);
    float a1r = c1r * inv1, a1i = c1i * inv1;

    ws[i]         = a0r;
    ws[N + i]     = a0i;
    ws[2 * N + i] = a1r;
    ws[3 * N + i] = a1i;
    if (i == 0) {
        float l0 = log1pf(expf(evl[0]));   // softplus
        float l1 = log1pf(expf(evl[1]));
        float inl = rsqrtf(l0 * l0 + l1 * l1);
        ws[4 * N]     = l0 * inl;
        ws[4 * N + 1] = l1 * inl;
    }
}

// ---------------------------------------------------------------------------
// Main: one block per basis operator k.
// v_k = sum_{i,j} conj(B_k[i,j]) * H[i,j],  H computed on the fly from LDS e's.
// H[i,j] = lam0*e0[i]*conj(e0[j]) - lam1*e1[i]*conj(e1[j])
// out += |v_k|^2
// ---------------------------------------------------------------------------
#define COMP(comp)                                                   \
    {                                                                \
        float x0r = e0ri * E0r.comp + e0ii * E0i.comp;               \
        float x0i = e0ii * E0r.comp - e0ri * E0i.comp;               \
        float x1r = e1ri * E1r.comp + e1ii * E1i.comp;               \
        float x1i = e1ii * E1r.comp - e1ri * E1i.comp;               \
        float hr = lam0 * x0r - lam1 * x1r;                          \
        float hi = lam0 * x0i - lam1 * x1i;                          \
        vr += a.comp * hr + b.comp * hi;                             \
        vi += a.comp * hi - b.comp * hr;                             \
    }

__global__ __launch_bounds__(256, 8) void main_kernel(
        const float4* __restrict__ br, const float4* __restrict__ bi,
        const float* __restrict__ ws, float* __restrict__ out) {
    __shared__ __align__(16) float le[4 * N];   // e0r | e0i | e1r | e1i
    __shared__ float slam[2];
    __shared__ float swr[4], swi[4];
    const int t = threadIdx.x;
    const int k = blockIdx.x;

    if (t < 128) {
        le[t]       = ws[t];
        le[t + 128] = ws[t + 128];
        le[t + 256] = ws[t + 256];
        le[t + 384] = ws[t + 384];
    }
    if (t < 2) slam[t] = ws[512 + t];
    __syncthreads();
    const float lam0 = slam[0], lam1 = slam[1];
    const float4* e0r4 = (const float4*)(le);
    const float4* e0i4 = (const float4*)(le + 128);
    const float4* e1r4 = (const float4*)(le + 256);
    const float4* e1i4 = (const float4*)(le + 384);

    const float4* brk = br + (size_t)k * (NN / 4);
    const float4* bik = bi + (size_t)k * (NN / 4);

    float vr = 0.f, vi = 0.f;
    float4 a0 = brk[t];
    float4 b0 = bik[t];
    #pragma unroll
    for (int c = 0; c < 16; ++c) {
        float4 a = a0, b = b0;
        if (c < 15) {                       // prefetch next chunk (depth-2 pipe)
            a0 = brk[t + 256 * (c + 1)];
            b0 = bik[t + 256 * (c + 1)];
        }
        const int it = t + 256 * c;
        const int i  = it >> 5;             // row (same for all 4 components)
        const int j4 = it & 31;             // float4 column index
        const float e0ri = le[i],       e0ii = le[128 + i];
        const float e1ri = le[256 + i], e1ii = le[384 + i];
        const float4 E0r = e0r4[j4], E0i = e0i4[j4];
        const float4 E1r = e1r4[j4], E1i = e1i4[j4];
        COMP(x) COMP(y) COMP(z) COMP(w)
    }

    // wave-64 reduce, then cross-wave via LDS
    for (int off = 32; off > 0; off >>= 1) {
        vr += __shfl_down(vr, off);
        vi += __shfl_down(vi, off);
    }
    const int wave = t >> 6, lane = t & 63;
    if (lane == 0) { swr[wave] = vr; swi[wave] = vi; }
    __syncthreads();
    if (t == 0) {
        float R = swr[0] + swr[1] + swr[2] + swr[3];
        float I = swi[0] + swi[1] + swi[2] + swi[3];
        atomicAdd(out, R * R + I * I);
    }
}

extern "C" void kernel_launch(void* const* d_in, const int* in_sizes, int n_in,
                              void* d_out, int out_size, void* d_ws, size_t ws_size,
                              hipStream_t stream) {
    const float* basis_re = (const float*)d_in[0];
    const float* basis_im = (const float*)d_in[1];
    const float* theta    = (const float*)d_in[2];
    const float* evl      = (const float*)d_in[3];
    float* out = (float*)d_out;
    float* ws  = (float*)d_ws;   // 514 floats

    hipMemsetAsync(d_out, 0, sizeof(float), stream);
    prep_kernel<<<1, 128, 0, stream>>>(theta, evl, ws);
    main_kernel<<<M, 256, 0, stream>>>((const float4*)basis_re,
                                       (const float4*)basis_im,
                                       ws, out);
}